// Round 1
// baseline (166.670 us; speedup 1.0000x reference)
//
#include <hip/hip_runtime.h>
#include <hip/hip_bf16.h>
#include <math.h>

// B=8, H=W=128, CH=64, OC=64, NCA_C=128, K=3, dils {1,2,4,8}, HID=64
// out: y [8,128,128,64] fp32 (8388608) then c2 [8,64] fp32 (512)
//
// Depthwise conv folded into GEMM1 over 33 positions (center-merged), fp8-e4m3
// (U scaled x256). Round-10: occupancy + pipeline restructure.
//  - 1024 blocks (1 row each), b=blk&7 XCD-local. LDS 32,256 B -> 4-5 blocks/CU
//    (round 9 was 512 blocks x 51 KB = 2/CU, Occupancy 18%, latency-bound).
//  - K-loop is a manual 2-stage ping-pong (A0/B0 <-> A1/B1): zero rotation
//    copies, no vmcnt(0) drain at the back-edge (round 9 paid ~24 v_mov + full
//    drain per position).
//  - prep1 folded into prep2 (blocks >=683 recompute c2 in-block): 2 launches.
// NO LDS / NO barriers in K-loop (rounds 5-7: spills/barriers/conflicts all lose).

typedef float  f32x4 __attribute__((ext_vector_type(4)));
typedef short  s16x8 __attribute__((ext_vector_type(8)));
typedef long   i64x2 __attribute__((ext_vector_type(2)));

static __device__ __forceinline__ unsigned short f2bf(float f) {
    __hip_bfloat16 h = __float2bfloat16(f);
    unsigned short u; __builtin_memcpy(&u, &h, 2); return u;
}
static __device__ __forceinline__ unsigned pk4fp8(float f0, float f1, float f2, float f3) {
    int v = 0;
    v = __builtin_amdgcn_cvt_pk_fp8_f32(f0, f1, v, false);
    v = __builtin_amdgcn_cvt_pk_fp8_f32(f2, f3, v, true);
    return (unsigned)v;
}

// xpad layout (fp8): [b][yy(144)][xx(144)][64 B: byte oct*16+kc2*8+j = ch kc2*32+oct*8+j]
#define XROWB  9216
#define XBATCH 1327104
#define USCALE 256.0f

// ---------------- prep2: c2 + xpad + pad + U + W2s + V + hcp (one grid) -----
__global__ void prep2(const float* __restrict__ x,  const float* __restrict__ pk,
                      const float* __restrict__ W1, const float* __restrict__ W2,
                      const float* __restrict__ b1,
                      const float* __restrict__ c,
                      const float* __restrict__ Wv, const float* __restrict__ bv,
                      const float* __restrict__ Wo, const float* __restrict__ bo,
                      const float* __restrict__ lng, const float* __restrict__ lnb,
                      unsigned char* __restrict__ xp, unsigned char* __restrict__ Uf,
                      unsigned short* __restrict__ W2s,
                      float* __restrict__ V, float* __restrict__ hcp,
                      float* __restrict__ outc2)
{
    const int blk = blockIdx.x, tid = threadIdx.x;
    __shared__ float sc[512], sv[512], c2s[512];

    if (blk >= 683) {
        // ---- in-block c2 (was prep1): each 64-lane wave handles one batch ----
        sc[tid] = c[tid]; sc[tid + 256] = c[tid + 256];
        __syncthreads();
        #pragma unroll
        for (int half = 0; half < 2; ++half) {
            int it = tid + half*256;
            int bb = it >> 6, j = it & 63;
            float v = bv[j];
            for (int i = 0; i < 64; ++i) v += sc[bb*64 + i]*Wv[i*64 + j];
            sv[it] = v;
        }
        __syncthreads();
        #pragma unroll
        for (int half = 0; half < 2; ++half) {
            int it = tid + half*256;
            int bb = it >> 6, j = it & 63;
            float t = bo[j] + sc[it];
            for (int i = 0; i < 64; ++i) t += sv[bb*64 + i]*Wo[i*64 + j];
            float s = t;
            for (int o = 32; o > 0; o >>= 1) s += __shfl_xor(s, o);
            float m = s * (1.f/64.f);
            float dq = (t - m)*(t - m);
            for (int o = 32; o > 0; o >>= 1) dq += __shfl_xor(dq, o);
            float a = (t - m) / sqrtf(dq*(1.f/64.f) + 1e-5f) * lng[j] + lnb[j];
            c2s[it] = sc[it] + a;
        }
        __syncthreads();
    }

    if (blk < 512) {
        // convert: one px per thread; byte order oct*16 + kc2*8 + j
        int i = blk*256 + tid;
        int xc = i & 127, y = (i >> 7) & 127, b = i >> 14;
        const float* src = x + (size_t)i*64;
        float4 f[16];
        #pragma unroll
        for (int k = 0; k < 16; ++k) f[k] = *(const float4*)(src + k*4);
        unsigned P[16];
        #pragma unroll
        for (int k = 0; k < 16; ++k) P[k] = pk4fp8(f[k].x, f[k].y, f[k].z, f[k].w);
        unsigned char* d = xp + (size_t)b*XBATCH + (size_t)(y+8)*XROWB + (size_t)(xc+8)*64;
        *(uint4*)(d +  0) = make_uint4(P[0], P[1], P[8],  P[9]);   // oct0: ch0-7, ch32-39
        *(uint4*)(d + 16) = make_uint4(P[2], P[3], P[10], P[11]);  // oct1: ch8-15, ch40-47
        *(uint4*)(d + 32) = make_uint4(P[4], P[5], P[12], P[13]);  // oct2
        *(uint4*)(d + 48) = make_uint4(P[6], P[7], P[14], P[15]);  // oct3
    } else if (blk < 648) {
        int idx = (blk - 512)*256 + tid;     // [0,34816) pad px
        int b = idx / 4352, r = idx - b*4352;
        int yy, xx;
        if (r < 2304) { int ry = r / 144; xx = r - ry*144; yy = (ry < 8) ? ry : 128 + ry; }
        else { int r2 = r - 2304; yy = 8 + (r2 >> 4); int xi = r2 & 15; xx = (xi < 8) ? xi : 128 + xi; }
        unsigned char* d = xp + (size_t)b*XBATCH + (size_t)yy*XROWB + (size_t)xx*64;
        uint4 z = make_uint4(0,0,0,0);
        *(uint4*)(d) = z; *(uint4*)(d+16) = z; *(uint4*)(d+32) = z; *(uint4*)(d+48) = z;
    } else if (blk < 681) {
        // U frags: idx = (pos*4 + nt)*64 + lane; 16 B per entry (kc2 0 | kc2 1)
        int idx = (blk - 648)*256 + tid;     // [0, 8448) = 33*4*64
        if (idx < 8448) {
            int lane = idx & 63, nt = (idx >> 6) & 3, pos = idx >> 8;
            int n  = nt*16 + (lane & 15);
            static constexpr int DI[33] = {3,3,3, 2,2,2, 1,1,1, 0,0,0, -1, 0,0, 1,1, 2,2, 3,3,
                                           0,0,0, 1,1,1, 2,2,2, 3,3,3};
            static constexpr int TT[33] = {0,1,2, 0,1,2, 0,1,2, 0,1,2, 4, 3,5, 3,5, 3,5, 3,5,
                                           6,7,8, 6,7,8, 6,7,8, 6,7,8};
            int di = DI[pos], t = TT[pos];
            float vv[16];
            #pragma unroll
            for (int kc2 = 0; kc2 < 2; ++kc2)
                #pragma unroll
                for (int j = 0; j < 8; ++j) {
                    int ch = kc2*32 + (lane >> 4)*8 + j;
                    float v;
                    if (di < 0) {               // merged center
                        v = W1[ch*64 + n];
                        for (int dd = 0; dd < 4; ++dd)
                            v += pk[(dd*128 + ch)*9 + 4] * W1[((1+dd)*128 + ch)*64 + n];
                    } else {
                        v = pk[(di*128 + ch)*9 + t] * W1[((1+di)*128 + ch)*64 + n];
                    }
                    vv[kc2*8 + j] = v * USCALE;
                }
            uint4 o;
            o.x = pk4fp8(vv[0],  vv[1],  vv[2],  vv[3]);
            o.y = pk4fp8(vv[4],  vv[5],  vv[6],  vv[7]);
            o.z = pk4fp8(vv[8],  vv[9],  vv[10], vv[11]);
            o.w = pk4fp8(vv[12], vv[13], vv[14], vv[15]);
            *(uint4*)(Uf + (size_t)idx*16) = o;
        }
    } else if (blk < 683) {
        int idx = (blk - 681)*256 + tid;     // [0,512)
        int lane = idx & 63, nt = (idx >> 6) & 3, kc2 = (idx >> 8) & 1;
        int n  = nt*16 + (lane & 15);
        int k0 = kc2*32 + (lane >> 4)*8;
        unsigned short e[8];
        #pragma unroll
        for (int j = 0; j < 8; ++j) e[j] = f2bf(W2[(k0+j)*64 + n]);
        uint4 o;
        o.x = (unsigned)e[0] | ((unsigned)e[1] << 16);
        o.y = (unsigned)e[2] | ((unsigned)e[3] << 16);
        o.z = (unsigned)e[4] | ((unsigned)e[5] << 16);
        o.w = (unsigned)e[6] | ((unsigned)e[7] << 16);
        *(uint4*)(W2s + (size_t)idx*8) = o;
    } else if (blk < 755) {
        int idx = (blk - 683)*256 + tid;     // [0, 18432) = 8*36*64
        int n = idx & 63, q = idx >> 6;
        int p = q % 36, b = q / 36;
        int di = p/9, t = p%9;
        float s = 0.f;
        for (int j = 0; j < 64; ++j)
            s += c2s[b*64 + j] * pk[(di*128 + 64 + j)*9 + t] * W1[((1+di)*128 + 64 + j)*64 + n];
        V[(size_t)q*64 + n] = s;
    } else {
        for (int it = tid; it < 512; it += 256) {
            int b = it >> 6, n = it & 63;
            float s = b1[n];
            for (int j = 0; j < 64; ++j) s += c2s[b*64 + j]*W1[(64 + j)*64 + n];
            hcp[it] = s;
            if (blk == 755) outc2[it] = c2s[it];
        }
    }
}

// ---------------- main fused kernel -----------------------------------------
#define HID_S 72

__global__ __launch_bounds__(256, 4) void nca_main(
    const unsigned char* __restrict__ xp,
    const unsigned char* __restrict__ U,
    const unsigned short* __restrict__ W2s,
    const float* __restrict__ V,
    const float* __restrict__ hcp,
    const float* __restrict__ b2,
    float* __restrict__ out)
{
    __shared__ unsigned short hid[128*HID_S]; // 18432 B
    __shared__ float V_l[36*64];              //  9216 B
    __shared__ float Cx_l[16*64];             //  4096 B
    __shared__ float Cy_l[64];                //   256 B
    __shared__ float hc2_l[64];               //   256 B  -> 32,256 B total

    const int tid = threadIdx.x;
    const int blk = blockIdx.x;
    const int b  = blk & 7;                   // XCD-local batch (1024 % 8 == 0)
    const int y  = blk >> 3;                  // one row per block

    // ---- tables ----
    {
        const float4* Vg = (const float4*)(V + (size_t)b*2304);
        for (int i = tid; i < 576; i += 256) ((float4*)V_l)[i] = Vg[i];
    }
    __syncthreads();
    for (int it = tid; it < 1024; it += 256) {      // Cx: x-edge correction
        int xi = it >> 6, n = it & 63;
        int xx = xi < 8 ? xi : 112 + xi;
        float s = 0.f;
        #pragma unroll
        for (int di = 0; di < 4; ++di) {
            int d = 1 << di;
            int dxo = (xx < d) ? 0 : ((xx >= 128 - d) ? 2 : -1);
            if (dxo >= 0) {
                s += V_l[(di*9 + 0*3 + dxo)*64 + n];
                s += V_l[(di*9 + 1*3 + dxo)*64 + n];
                s += V_l[(di*9 + 2*3 + dxo)*64 + n];
            }
        }
        Cx_l[it] = s;
    }
    if (tid < 64) {                                 // Cy for this block's row
        int n = tid;
        float s = 0.f;
        #pragma unroll
        for (int di = 0; di < 4; ++di) {
            int d = 1 << di;
            int dyo = (y < d) ? 0 : ((y >= 128 - d) ? 2 : -1);
            if (dyo >= 0) {
                s += V_l[(di*9 + dyo*3 + 0)*64 + n];
                s += V_l[(di*9 + dyo*3 + 1)*64 + n];
                s += V_l[(di*9 + dyo*3 + 2)*64 + n];
            }
        }
        Cy_l[n] = s;
    } else if (tid < 128) {
        int n = tid - 64;
        float s = hcp[b*64 + n];
        for (int p = 0; p < 36; ++p) s += V_l[p*64 + n];
        hc2_l[n] = s;
    }
    __syncthreads();

    // ---- geometry: wave w owns px x in [w*32, w*32+32) of row y ----
    const int lane = tid & 63;
    const int w    = tid >> 6;
    const int xw   = w * 32;
    const int ln15 = lane & 15;
    const int oct  = lane >> 4;

    // A: one dwordx4 per mt = both kc2 fragments (bytes oct*16..+15 of the px)
    const unsigned char* abase = xp + (size_t)b*XBATCH + (size_t)(y + 8)*XROWB
                               + (size_t)(xw + ln15 + 8)*64 + oct*16;
    const unsigned char* ubase = U + (size_t)lane*16;

    f32x4 acc[2][4];
    #pragma unroll
    for (int mt = 0; mt < 2; ++mt)
        #pragma unroll
        for (int nt = 0; nt < 4; ++nt) {
            acc[mt][nt][0] = 0.f; acc[mt][nt][1] = 0.f;
            acc[mt][nt][2] = 0.f; acc[mt][nt][3] = 0.f;
        }

    // byte offsets (px stride 64 B), order matches prep2 U pos order
    static constexpr int OFF[33] = {
        (-8*144-8)*64, (-8*144)*64, (-8*144+8)*64,
        (-4*144-4)*64, (-4*144)*64, (-4*144+4)*64,
        (-2*144-2)*64, (-2*144)*64, (-2*144+2)*64,
        (-1*144-1)*64, (-1*144)*64, (-1*144+1)*64,
        0,
        -64, 64, -128, 128, -256, 256, -512, 512,
        ( 1*144-1)*64, ( 1*144)*64, ( 1*144+1)*64,
        ( 2*144-2)*64, ( 2*144)*64, ( 2*144+2)*64,
        ( 4*144-4)*64, ( 4*144)*64, ( 4*144+4)*64,
        ( 8*144-8)*64, ( 8*144)*64, ( 8*144+8)*64
    };

    auto load_AB = [&](int pos, i64x2* A, i64x2* Bv) {
        const unsigned char* rp = abase + OFF[pos];
        #pragma unroll
        for (int mt = 0; mt < 2; ++mt) A[mt] = *(const i64x2*)(rp + mt*1024);
        const unsigned char* up = ubase + (size_t)pos*4096;
        #pragma unroll
        for (int nt = 0; nt < 4; ++nt) Bv[nt] = *(const i64x2*)(up + nt*1024);
    };
    auto mfma_step = [&](const i64x2* A, const i64x2* Bv) {
        #pragma unroll
        for (int kc2 = 0; kc2 < 2; ++kc2)
            #pragma unroll
            for (int nt = 0; nt < 4; ++nt) {
                long bf = Bv[nt][kc2];
                #pragma unroll
                for (int mt = 0; mt < 2; ++mt)
                    acc[mt][nt] = __builtin_amdgcn_mfma_f32_16x16x32_fp8_fp8(A[mt][kc2], bf, acc[mt][nt], 0, 0, 0);
            }
    };

    // 2-stage ping-pong over 33 positions: no register rotation copies,
    // distance-1 prefetch, counted vmcnt at use instead of a back-edge drain.
    i64x2 A0[2], A1[2], B0[4], B1[4];
    load_AB(0, A0, B0);
    #pragma unroll 1
    for (int it2 = 0; it2 < 16; ++it2) {
        load_AB(2*it2 + 1, A1, B1);
        mfma_step(A0, B0);
        load_AB(2*it2 + 2, A0, B0);
        mfma_step(A1, B1);
    }
    mfma_step(A0, B0);                        // pos 32

    // ---- epilogue 1: acc/256 + hc2 - corrections, GELU, write hid (bf16) ----
    const bool yedge = (y < 8) || (y >= 120);
    #pragma unroll
    for (int mt = 0; mt < 2; ++mt) {
        #pragma unroll
        for (int nt = 0; nt < 4; ++nt) {
            const int n = nt*16 + ln15;
            const float hcv = hc2_l[n];
            const float cyv = yedge ? Cy_l[n] : 0.f;
            #pragma unroll
            for (int r = 0; r < 4; ++r) {
                int m = oct*4 + r;                  // C row = (lane>>4)*4 + reg
                int x = xw + mt*16 + m;
                float h = acc[mt][nt][r]*(1.0f/USCALE) + hcv - cyv;
                if (x < 8 || x >= 120) {
                    int xi = (x < 8) ? x : (x - 112);
                    h -= Cx_l[xi*64 + n];
                    if (yedge) {                    // corner double-subtract fix
                        #pragma unroll
                        for (int di = 0; di < 4; ++di) {
                            int d = 1 << di;
                            int dyo = (y < d) ? 0 : ((y >= 128 - d) ? 2 : -1);
                            int dxo = (x < d) ? 0 : ((x >= 128 - d) ? 2 : -1);
                            if (dyo >= 0 && dxo >= 0)
                                h += V_l[(di*9 + dyo*3 + dxo)*64 + n];
                        }
                    }
                }
                float u = 0.7978845608028654f * (h + 0.044715f*h*h*h);
                float g = h / (1.f + __expf(-2.f*u));
                hid[x*HID_S + n] = f2bf(g);
            }
        }
    }
    // each wave reads back only its own 32 hid rows -> no barrier needed

    // ---- GEMM2: y = hid @ W2 + b2 (bf16) ----
    f32x4 acc2[2][4];
    #pragma unroll
    for (int mt = 0; mt < 2; ++mt)
        #pragma unroll
        for (int nt = 0; nt < 4; ++nt) {
            acc2[mt][nt][0] = 0.f; acc2[mt][nt][1] = 0.f;
            acc2[mt][nt][2] = 0.f; acc2[mt][nt][3] = 0.f;
        }
    #pragma unroll
    for (int kc2 = 0; kc2 < 2; ++kc2) {
        s16x8 a2[2];
        #pragma unroll
        for (int mt = 0; mt < 2; ++mt)
            a2[mt] = *(const s16x8*)&hid[(xw + mt*16 + ln15)*HID_S + kc2*32 + oct*8];
        #pragma unroll
        for (int nt = 0; nt < 4; ++nt) {
            s16x8 bf = *(const s16x8*)(W2s + ((size_t)(kc2*4 + nt)*64 + lane)*8);
            #pragma unroll
            for (int mt = 0; mt < 2; ++mt)
                acc2[mt][nt] = __builtin_amdgcn_mfma_f32_16x16x32_bf16(a2[mt], bf, acc2[mt][nt], 0, 0, 0);
        }
    }

    float* ob = out + ((size_t)(b*128 + y))*128*64;
    #pragma unroll
    for (int nt = 0; nt < 4; ++nt) {
        const float b2v = b2[nt*16 + ln15];
        #pragma unroll
        for (int mt = 0; mt < 2; ++mt) {
            #pragma unroll
            for (int r = 0; r < 4; ++r) {
                int x = xw + mt*16 + oct*4 + r;
                ob[(size_t)x*64 + nt*16 + ln15] = acc2[mt][nt][r] + b2v;
            }
        }
    }
}

// ---------------- launch ----------------------------------------------------
extern "C" void kernel_launch(void* const* d_in, const int* in_sizes, int n_in,
                              void* d_out, int out_size, void* d_ws, size_t ws_size,
                              hipStream_t stream) {
    const float* x   = (const float*)d_in[0];
    const float* c   = (const float*)d_in[1];
    // d_in[2..5] = Wq,bq,Wk,bk : unused (softmax weights sum to 1 -> pool == v)
    const float* Wv  = (const float*)d_in[6];
    const float* bv  = (const float*)d_in[7];
    const float* Wo  = (const float*)d_in[8];
    const float* bo  = (const float*)d_in[9];
    const float* lng = (const float*)d_in[10];
    const float* lnb = (const float*)d_in[11];
    const float* pk  = (const float*)d_in[12];
    const float* W1  = (const float*)d_in[13];
    const float* b1  = (const float*)d_in[14];
    const float* W2  = (const float*)d_in[15];
    const float* b2  = (const float*)d_in[16];
    float* out = (float*)d_out;

    char* w = (char*)d_ws;
    unsigned char*  xpb = (unsigned char*)(w);                   // 10,616,832 B
    unsigned char*  Uf  = (unsigned char*)(w + 10616832);        //    135,168 B
    unsigned short* W2s = (unsigned short*)(w + 10752000);       //      8,192 B
    float*          V   = (float*)         (w + 10760192);       //     73,728 B
    float*          hcp = (float*)         (w + 10833920);       //      2,048 B (end 10,835,968)

    prep2<<<757, 256, 0, stream>>>(x, pk, W1, W2, b1, c, Wv, bv, Wo, bo, lng, lnb,
                                   xpb, Uf, W2s, V, hcp, out + 8388608);
    nca_main<<<1024, 256, 0, stream>>>(xpb, Uf, W2s, V, hcp, b2, out);
}

// Round 2
// 154.506 us; speedup vs baseline: 1.0787x; 1.0787x over previous
//
#include <hip/hip_runtime.h>
#include <hip/hip_bf16.h>
#include <math.h>

// B=8, H=W=128, CH=64, OC=64, NCA_C=128, K=3, dils {1,2,4,8}, HID=64
// out: y [8,128,128,64] fp32 (8388608) then c2 [8,64] fp32 (512)
//
// Depthwise conv folded into GEMM1 over 33 positions (center-merged), fp8-e4m3
// (U scaled x256). Round-11: LDS-staged B-panels.
//  - Round-10 post-mortem: U (132 KB) was re-read per WAVE from L2 (553 MB/launch,
//    2x round-9); occupancy up but MfmaUtil down -> redundant-B-traffic/latency
//    bound, not occupancy bound.
//  - Now: 512 blocks x 8 waves (2 rows, M=32/wave, 16 waves/CU). U staged in
//    double-buffered LDS K-panels of 4 positions (16 KB x2) via global_load_lds;
//    ONE barrier per K-block (9 total), 64 MFMA/wave between barriers.
//    B from L2: 553 MB -> 69 MB. B reads = conflict-free ds_read_b128.
//  - A register ping-pong distance-1, compile-time parity (no rotation copies).
//  - hid LDS region unions with the U panels (publish barrier after K-loop).
//  - s_setprio(1) around MFMA clusters (2 desynced blocks/CU).

typedef float  f32x4 __attribute__((ext_vector_type(4)));
typedef short  s16x8 __attribute__((ext_vector_type(8)));
typedef long   i64x2 __attribute__((ext_vector_type(2)));

static __device__ __forceinline__ unsigned short f2bf(float f) {
    __hip_bfloat16 h = __float2bfloat16(f);
    unsigned short u; __builtin_memcpy(&u, &h, 2); return u;
}
static __device__ __forceinline__ unsigned pk4fp8(float f0, float f1, float f2, float f3) {
    int v = 0;
    v = __builtin_amdgcn_cvt_pk_fp8_f32(f0, f1, v, false);
    v = __builtin_amdgcn_cvt_pk_fp8_f32(f2, f3, v, true);
    return (unsigned)v;
}

// xpad layout (fp8): [b][yy(144)][xx(144)][64 B: byte oct*16+kc2*8+j = ch kc2*32+oct*8+j]
#define XROWB  9216
#define XBATCH 1327104
#define USCALE 256.0f

// ---------------- prep2: c2 + xpad + pad + U + W2s + V + hcp (one grid) -----
__global__ void prep2(const float* __restrict__ x,  const float* __restrict__ pk,
                      const float* __restrict__ W1, const float* __restrict__ W2,
                      const float* __restrict__ b1,
                      const float* __restrict__ c,
                      const float* __restrict__ Wv, const float* __restrict__ bv,
                      const float* __restrict__ Wo, const float* __restrict__ bo,
                      const float* __restrict__ lng, const float* __restrict__ lnb,
                      unsigned char* __restrict__ xp, unsigned char* __restrict__ Uf,
                      unsigned short* __restrict__ W2s,
                      float* __restrict__ V, float* __restrict__ hcp,
                      float* __restrict__ outc2)
{
    const int blk = blockIdx.x, tid = threadIdx.x;
    __shared__ float sc[512], sv[512], c2s[512];

    if (blk >= 683) {
        // ---- in-block c2 (was prep1): each 64-lane wave handles one batch ----
        sc[tid] = c[tid]; sc[tid + 256] = c[tid + 256];
        __syncthreads();
        #pragma unroll
        for (int half = 0; half < 2; ++half) {
            int it = tid + half*256;
            int bb = it >> 6, j = it & 63;
            float v = bv[j];
            for (int i = 0; i < 64; ++i) v += sc[bb*64 + i]*Wv[i*64 + j];
            sv[it] = v;
        }
        __syncthreads();
        #pragma unroll
        for (int half = 0; half < 2; ++half) {
            int it = tid + half*256;
            int bb = it >> 6, j = it & 63;
            float t = bo[j] + sc[it];
            for (int i = 0; i < 64; ++i) t += sv[bb*64 + i]*Wo[i*64 + j];
            float s = t;
            for (int o = 32; o > 0; o >>= 1) s += __shfl_xor(s, o);
            float m = s * (1.f/64.f);
            float dq = (t - m)*(t - m);
            for (int o = 32; o > 0; o >>= 1) dq += __shfl_xor(dq, o);
            float a = (t - m) / sqrtf(dq*(1.f/64.f) + 1e-5f) * lng[j] + lnb[j];
            c2s[it] = sc[it] + a;
        }
        __syncthreads();
    }

    if (blk < 512) {
        // convert: one px per thread; byte order oct*16 + kc2*8 + j
        int i = blk*256 + tid;
        int xc = i & 127, y = (i >> 7) & 127, b = i >> 14;
        const float* src = x + (size_t)i*64;
        float4 f[16];
        #pragma unroll
        for (int k = 0; k < 16; ++k) f[k] = *(const float4*)(src + k*4);
        unsigned P[16];
        #pragma unroll
        for (int k = 0; k < 16; ++k) P[k] = pk4fp8(f[k].x, f[k].y, f[k].z, f[k].w);
        unsigned char* d = xp + (size_t)b*XBATCH + (size_t)(y+8)*XROWB + (size_t)(xc+8)*64;
        *(uint4*)(d +  0) = make_uint4(P[0], P[1], P[8],  P[9]);   // oct0: ch0-7, ch32-39
        *(uint4*)(d + 16) = make_uint4(P[2], P[3], P[10], P[11]);  // oct1: ch8-15, ch40-47
        *(uint4*)(d + 32) = make_uint4(P[4], P[5], P[12], P[13]);  // oct2
        *(uint4*)(d + 48) = make_uint4(P[6], P[7], P[14], P[15]);  // oct3
    } else if (blk < 648) {
        int idx = (blk - 512)*256 + tid;     // [0,34816) pad px
        int b = idx / 4352, r = idx - b*4352;
        int yy, xx;
        if (r < 2304) { int ry = r / 144; xx = r - ry*144; yy = (ry < 8) ? ry : 128 + ry; }
        else { int r2 = r - 2304; yy = 8 + (r2 >> 4); int xi = r2 & 15; xx = (xi < 8) ? xi : 128 + xi; }
        unsigned char* d = xp + (size_t)b*XBATCH + (size_t)yy*XROWB + (size_t)xx*64;
        uint4 z = make_uint4(0,0,0,0);
        *(uint4*)(d) = z; *(uint4*)(d+16) = z; *(uint4*)(d+32) = z; *(uint4*)(d+48) = z;
    } else if (blk < 681) {
        // U frags: idx = (pos*4 + nt)*64 + lane; 16 B per entry (kc2 0 | kc2 1)
        int idx = (blk - 648)*256 + tid;     // [0, 8448) = 33*4*64
        if (idx < 8448) {
            int lane = idx & 63, nt = (idx >> 6) & 3, pos = idx >> 8;
            int n  = nt*16 + (lane & 15);
            static constexpr int DI[33] = {3,3,3, 2,2,2, 1,1,1, 0,0,0, -1, 0,0, 1,1, 2,2, 3,3,
                                           0,0,0, 1,1,1, 2,2,2, 3,3,3};
            static constexpr int TT[33] = {0,1,2, 0,1,2, 0,1,2, 0,1,2, 4, 3,5, 3,5, 3,5, 3,5,
                                           6,7,8, 6,7,8, 6,7,8, 6,7,8};
            int di = DI[pos], t = TT[pos];
            float vv[16];
            #pragma unroll
            for (int kc2 = 0; kc2 < 2; ++kc2)
                #pragma unroll
                for (int j = 0; j < 8; ++j) {
                    int ch = kc2*32 + (lane >> 4)*8 + j;
                    float v;
                    if (di < 0) {               // merged center
                        v = W1[ch*64 + n];
                        for (int dd = 0; dd < 4; ++dd)
                            v += pk[(dd*128 + ch)*9 + 4] * W1[((1+dd)*128 + ch)*64 + n];
                    } else {
                        v = pk[(di*128 + ch)*9 + t] * W1[((1+di)*128 + ch)*64 + n];
                    }
                    vv[kc2*8 + j] = v * USCALE;
                }
            uint4 o;
            o.x = pk4fp8(vv[0],  vv[1],  vv[2],  vv[3]);
            o.y = pk4fp8(vv[4],  vv[5],  vv[6],  vv[7]);
            o.z = pk4fp8(vv[8],  vv[9],  vv[10], vv[11]);
            o.w = pk4fp8(vv[12], vv[13], vv[14], vv[15]);
            *(uint4*)(Uf + (size_t)idx*16) = o;
        }
    } else if (blk < 683) {
        int idx = (blk - 681)*256 + tid;     // [0,512)
        int lane = idx & 63, nt = (idx >> 6) & 3, kc2 = (idx >> 8) & 1;
        int n  = nt*16 + (lane & 15);
        int k0 = kc2*32 + (lane >> 4)*8;
        unsigned short e[8];
        #pragma unroll
        for (int j = 0; j < 8; ++j) e[j] = f2bf(W2[(k0+j)*64 + n]);
        uint4 o;
        o.x = (unsigned)e[0] | ((unsigned)e[1] << 16);
        o.y = (unsigned)e[2] | ((unsigned)e[3] << 16);
        o.z = (unsigned)e[4] | ((unsigned)e[5] << 16);
        o.w = (unsigned)e[6] | ((unsigned)e[7] << 16);
        *(uint4*)(W2s + (size_t)idx*8) = o;
    } else if (blk < 755) {
        int idx = (blk - 683)*256 + tid;     // [0, 18432) = 8*36*64
        int n = idx & 63, q = idx >> 6;
        int p = q % 36, b = q / 36;
        int di = p/9, t = p%9;
        float s = 0.f;
        for (int j = 0; j < 64; ++j)
            s += c2s[b*64 + j] * pk[(di*128 + 64 + j)*9 + t] * W1[((1+di)*128 + 64 + j)*64 + n];
        V[(size_t)q*64 + n] = s;
    } else {
        for (int it = tid; it < 512; it += 256) {
            int b = it >> 6, n = it & 63;
            float s = b1[n];
            for (int j = 0; j < 64; ++j) s += c2s[b*64 + j]*W1[(64 + j)*64 + n];
            hcp[it] = s;
            if (blk == 755) outc2[it] = c2s[it];
        }
    }
}

// ---------------- main fused kernel -----------------------------------------
#define HID_S 72

__global__ __launch_bounds__(512, 4) void nca_main(
    const unsigned char* __restrict__ xp,
    const unsigned char* __restrict__ U,
    const unsigned short* __restrict__ W2s,
    const float* __restrict__ V,
    const float* __restrict__ hcp,
    const float* __restrict__ b2,
    float* __restrict__ out)
{
    // smem: during K-loop = U double-buffer (2 x 16384); after = hid 256*72*2
    __shared__ __align__(16) unsigned char smem[36864];
    __shared__ float V_l[36*64];              //  9216 B
    __shared__ float Cx_l[16*64];             //  4096 B
    __shared__ float Cy_l[2*64];              //   512 B
    __shared__ float hc2_l[64];               //   256 B  -> 50,944 B total

    unsigned short* hid = (unsigned short*)smem;

    const int tid = threadIdx.x;
    const int blk = blockIdx.x;
    const int b  = blk & 7;                   // XCD-local batch (512 % 8 == 0)
    const int y0 = (blk >> 3) * 2;            // two rows per block

    // ---- stage K-block 0 (pos 0..3, 16 KB) into buffer 0 (DMA, async) ----
    #pragma unroll
    for (int s = 0; s < 2; ++s) {
        int off = tid*16 + s*8192;
        __builtin_amdgcn_global_load_lds(
            (const __attribute__((address_space(1))) unsigned int*)(U + off),
            (__attribute__((address_space(3))) unsigned int*)(smem + off),
            16, 0, 0);
    }

    // ---- tables ----
    {
        const float4* Vg = (const float4*)(V + (size_t)b*2304);
        for (int i = tid; i < 576; i += 512) ((float4*)V_l)[i] = Vg[i];
    }
    __syncthreads();
    for (int it = tid; it < 1024; it += 512) {      // Cx: x-edge correction
        int xi = it >> 6, n = it & 63;
        int xx = xi < 8 ? xi : 112 + xi;
        float s = 0.f;
        #pragma unroll
        for (int di = 0; di < 4; ++di) {
            int d = 1 << di;
            int dxo = (xx < d) ? 0 : ((xx >= 128 - d) ? 2 : -1);
            if (dxo >= 0) {
                s += V_l[(di*9 + 0*3 + dxo)*64 + n];
                s += V_l[(di*9 + 1*3 + dxo)*64 + n];
                s += V_l[(di*9 + 2*3 + dxo)*64 + n];
            }
        }
        Cx_l[it] = s;
    }
    if (tid < 128) {                                // Cy for this block's 2 rows
        int r = tid >> 6, n = tid & 63;
        int yy = y0 + r;
        float s = 0.f;
        #pragma unroll
        for (int di = 0; di < 4; ++di) {
            int d = 1 << di;
            int dyo = (yy < d) ? 0 : ((yy >= 128 - d) ? 2 : -1);
            if (dyo >= 0) {
                s += V_l[(di*9 + dyo*3 + 0)*64 + n];
                s += V_l[(di*9 + dyo*3 + 1)*64 + n];
                s += V_l[(di*9 + dyo*3 + 2)*64 + n];
            }
        }
        Cy_l[tid] = s;
    } else if (tid < 192) {
        int n = tid - 128;
        float s = hcp[b*64 + n];
        for (int p = 0; p < 36; ++p) s += V_l[p*64 + n];
        hc2_l[n] = s;
    }
    __syncthreads();   // publishes U K-block 0 (vmcnt drained) + tables

    // ---- geometry: wave w -> row y0+(w>>2), x in [(w&3)*32, +32) ----
    const int lane = tid & 63;
    const int w    = tid >> 6;
    const int rib  = w >> 2;                  // row in block
    const int y    = y0 + rib;
    const int xw   = (w & 3) * 32;
    const int ln15 = lane & 15;
    const int oct  = lane >> 4;

    const unsigned char* abase = xp + (size_t)b*XBATCH + (size_t)(y + 8)*XROWB
                               + (size_t)(xw + ln15 + 8)*64 + oct*16;

    f32x4 acc[2][4];
    #pragma unroll
    for (int mt = 0; mt < 2; ++mt)
        #pragma unroll
        for (int nt = 0; nt < 4; ++nt) {
            acc[mt][nt][0] = 0.f; acc[mt][nt][1] = 0.f;
            acc[mt][nt][2] = 0.f; acc[mt][nt][3] = 0.f;
        }

    // byte offsets (px stride 64 B), order matches prep2 U pos order
    static constexpr int OFF[33] = {
        (-8*144-8)*64, (-8*144)*64, (-8*144+8)*64,
        (-4*144-4)*64, (-4*144)*64, (-4*144+4)*64,
        (-2*144-2)*64, (-2*144)*64, (-2*144+2)*64,
        (-1*144-1)*64, (-1*144)*64, (-1*144+1)*64,
        0,
        -64, 64, -128, 128, -256, 256, -512, 512,
        ( 1*144-1)*64, ( 1*144)*64, ( 1*144+1)*64,
        ( 2*144-2)*64, ( 2*144)*64, ( 2*144+2)*64,
        ( 4*144-4)*64, ( 4*144)*64, ( 4*144+4)*64,
        ( 8*144-8)*64, ( 8*144)*64, ( 8*144+8)*64
    };

    auto loadA = [&](int pos, i64x2* A) {
        const unsigned char* rp = abase + OFF[pos];
        A[0] = *(const i64x2*)(rp);
        A[1] = *(const i64x2*)(rp + 1024);
    };
    auto loadB = [&](int bufofs, int p, i64x2* Bv) {
        const unsigned char* rp = smem + bufofs + p*4096 + lane*16;
        #pragma unroll
        for (int nt = 0; nt < 4; ++nt) Bv[nt] = *(const i64x2*)(rp + nt*1024);
    };
    auto mfma_step = [&](const i64x2* A, const i64x2* Bv) {
        #pragma unroll
        for (int kc2 = 0; kc2 < 2; ++kc2)
            #pragma unroll
            for (int nt = 0; nt < 4; ++nt) {
                long bfr = Bv[nt][kc2];
                #pragma unroll
                for (int mt = 0; mt < 2; ++mt)
                    acc[mt][nt] = __builtin_amdgcn_mfma_f32_16x16x32_fp8_fp8(A[mt][kc2], bfr, acc[mt][nt], 0, 0, 0);
            }
    };

    // K-loop: 8 K-blocks of 4 positions + tail pos 32. One barrier per K-block.
    i64x2 Areg[2][2], Breg[2][4];
    loadA(0, Areg[0]);
    loadB(0, 0, Breg[0]);

    int cur = 0;
    #pragma unroll 1
    for (int kb = 0; kb < 8; ++kb) {
        {   // stage next K-block into the other buffer (DMA, linear layout)
            const int nbytes = (kb < 7) ? 16384 : 4096;
            const unsigned char* gsrc = U + (size_t)(kb + 1)*16384;
            unsigned char* ldst = smem + (cur ^ 1)*16384;
            for (int off = tid*16; off < nbytes; off += 8192)
                __builtin_amdgcn_global_load_lds(
                    (const __attribute__((address_space(1))) unsigned int*)(gsrc + off),
                    (__attribute__((address_space(3))) unsigned int*)(ldst + off),
                    16, 0, 0);
        }
        const int cofs = cur*16384;
        #pragma unroll
        for (int p = 0; p < 4; ++p) {
            const int pos = kb*4 + p;
            loadA(pos + 1, Areg[(p + 1) & 1]);             // A prefetch dist-1
            if (p < 3) loadB(cofs, p + 1, Breg[(p + 1) & 1]); // B prefetch dist-1
            __builtin_amdgcn_s_setprio(1);
            mfma_step(Areg[p & 1], Breg[p & 1]);
            __builtin_amdgcn_s_setprio(0);
        }
        __syncthreads();          // drains this wave's DMA + publishes buffer
        cur ^= 1;
        loadB(cur*16384, 0, Breg[0]);                      // first B of next block
    }
    // tail: pos 32 (Areg[0] prefetched at kb=7,p=3; Breg[0] just loaded)
    __builtin_amdgcn_s_setprio(1);
    mfma_step(Areg[0], Breg[0]);
    __builtin_amdgcn_s_setprio(0);
    __syncthreads();              // all U reads done -> safe to overwrite as hid

    // ---- epilogue 1: acc/256 + hc2 - corrections, GELU, write hid (bf16) ----
    const bool yedge = (y < 8) || (y >= 120);
    #pragma unroll
    for (int mt = 0; mt < 2; ++mt) {
        #pragma unroll
        for (int nt = 0; nt < 4; ++nt) {
            const int n = nt*16 + ln15;
            const float hcv = hc2_l[n];
            const float cyv = yedge ? Cy_l[rib*64 + n] : 0.f;
            #pragma unroll
            for (int r = 0; r < 4; ++r) {
                int m = oct*4 + r;                  // C row = (lane>>4)*4 + reg
                int x = xw + mt*16 + m;
                float h = acc[mt][nt][r]*(1.0f/USCALE) + hcv - cyv;
                if (x < 8 || x >= 120) {
                    int xi = (x < 8) ? x : (x - 112);
                    h -= Cx_l[xi*64 + n];
                    if (yedge) {                    // corner double-subtract fix
                        #pragma unroll
                        for (int di = 0; di < 4; ++di) {
                            int d = 1 << di;
                            int dyo = (y < d) ? 0 : ((y >= 128 - d) ? 2 : -1);
                            int dxo = (x < d) ? 0 : ((x >= 128 - d) ? 2 : -1);
                            if (dyo >= 0 && dxo >= 0)
                                h += V_l[(di*9 + dyo*3 + dxo)*64 + n];
                        }
                    }
                }
                float u = 0.7978845608028654f * (h + 0.044715f*h*h*h);
                float g = h / (1.f + __expf(-2.f*u));
                hid[(rib*128 + x)*HID_S + n] = f2bf(g);
            }
        }
    }
    // each wave reads back only its own 32 hid rows -> no barrier needed

    // ---- GEMM2: y = hid @ W2 + b2 (bf16) ----
    f32x4 acc2[2][4];
    #pragma unroll
    for (int mt = 0; mt < 2; ++mt)
        #pragma unroll
        for (int nt = 0; nt < 4; ++nt) {
            acc2[mt][nt][0] = 0.f; acc2[mt][nt][1] = 0.f;
            acc2[mt][nt][2] = 0.f; acc2[mt][nt][3] = 0.f;
        }
    #pragma unroll
    for (int kc2 = 0; kc2 < 2; ++kc2) {
        s16x8 a2[2];
        #pragma unroll
        for (int mt = 0; mt < 2; ++mt)
            a2[mt] = *(const s16x8*)&hid[(rib*128 + xw + mt*16 + ln15)*HID_S + kc2*32 + oct*8];
        #pragma unroll
        for (int nt = 0; nt < 4; ++nt) {
            s16x8 bfr = *(const s16x8*)(W2s + ((size_t)(kc2*4 + nt)*64 + lane)*8);
            #pragma unroll
            for (int mt = 0; mt < 2; ++mt)
                acc2[mt][nt] = __builtin_amdgcn_mfma_f32_16x16x32_bf16(a2[mt], bfr, acc2[mt][nt], 0, 0, 0);
        }
    }

    float* ob = out + ((size_t)(b*128 + y))*128*64;
    #pragma unroll
    for (int nt = 0; nt < 4; ++nt) {
        const float b2v = b2[nt*16 + ln15];
        #pragma unroll
        for (int mt = 0; mt < 2; ++mt) {
            #pragma unroll
            for (int r = 0; r < 4; ++r) {
                int x = xw + mt*16 + oct*4 + r;
                ob[(size_t)x*64 + nt*16 + ln15] = acc2[mt][nt][r] + b2v;
            }
        }
    }
}

// ---------------- launch ----------------------------------------------------
extern "C" void kernel_launch(void* const* d_in, const int* in_sizes, int n_in,
                              void* d_out, int out_size, void* d_ws, size_t ws_size,
                              hipStream_t stream) {
    const float* x   = (const float*)d_in[0];
    const float* c   = (const float*)d_in[1];
    // d_in[2..5] = Wq,bq,Wk,bk : unused (softmax weights sum to 1 -> pool == v)
    const float* Wv  = (const float*)d_in[6];
    const float* bv  = (const float*)d_in[7];
    const float* Wo  = (const float*)d_in[8];
    const float* bo  = (const float*)d_in[9];
    const float* lng = (const float*)d_in[10];
    const float* lnb = (const float*)d_in[11];
    const float* pk  = (const float*)d_in[12];
    const float* W1  = (const float*)d_in[13];
    const float* b1  = (const float*)d_in[14];
    const float* W2  = (const float*)d_in[15];
    const float* b2  = (const float*)d_in[16];
    float* out = (float*)d_out;

    char* w = (char*)d_ws;
    unsigned char*  xpb = (unsigned char*)(w);                   // 10,616,832 B
    unsigned char*  Uf  = (unsigned char*)(w + 10616832);        //    135,168 B
    unsigned short* W2s = (unsigned short*)(w + 10752000);       //      8,192 B
    float*          V   = (float*)         (w + 10760192);       //     73,728 B
    float*          hcp = (float*)         (w + 10833920);       //      2,048 B (end 10,835,968)

    prep2<<<757, 256, 0, stream>>>(x, pk, W1, W2, b1, c, Wv, bv, Wo, bo, lng, lnb,
                                   xpb, Uf, W2s, V, hcp, out + 8388608);
    nca_main<<<512, 512, 0, stream>>>(xpb, Uf, W2s, V, hcp, b2, out);
}

// Round 3
// 150.279 us; speedup vs baseline: 1.1091x; 1.0281x over previous
//
#include <hip/hip_runtime.h>
#include <hip/hip_bf16.h>
#include <math.h>

// B=8, H=W=128, CH=64, OC=64, NCA_C=128, K=3, dils {1,2,4,8}, HID=64
// out: y [8,128,128,64] fp32 (8388608) then c2 [8,64] fp32 (512)
//
// Depthwise conv folded into GEMM1 over 33 positions (center-merged), fp8-e4m3
// (U scaled x256). Round-12: MX-scaled MFMA + coalesced prep.
//  - GEMM1 now uses mfma_scale_f32_32x32x64_f8f6f4 with unit E8M0 scales
//    (0x7F per byte): 2x the non-scaled fp8 rate, 66 MFMA/wave vs 528.
//    A: 32 B/lane plain-ch-order (k = (lane>>5)*32 + j), one i32x8 load.
//    B: U in [pos][nt][half][lane][16B] layout -> 4 conflict-free ds_read_b128
//    per pos (32 B/lane stride would be a 16-way bank conflict).
//  - K-block = 8 positions (32 KB x2 LDS double-buffer), 5 barriers total.
//  - prep2 convert restructured: 16 lanes/px, one float4 load (1 KB/wave
//    contiguous) + one dword store (256 B/wave contiguous) -> removes the 4x
//    L2-transaction inflation of the old 256 B/lane scheme.
// NO register rotation copies anywhere (compile-time parity ping-pong).

typedef float  f32x4  __attribute__((ext_vector_type(4)));
typedef float  f32x16 __attribute__((ext_vector_type(16)));
typedef short  s16x8  __attribute__((ext_vector_type(8)));
typedef int    i32x4  __attribute__((ext_vector_type(4)));
typedef int    i32x8  __attribute__((ext_vector_type(8)));

static __device__ __forceinline__ unsigned short f2bf(float f) {
    __hip_bfloat16 h = __float2bfloat16(f);
    unsigned short u; __builtin_memcpy(&u, &h, 2); return u;
}
static __device__ __forceinline__ unsigned pk4fp8(float f0, float f1, float f2, float f3) {
    int v = 0;
    v = __builtin_amdgcn_cvt_pk_fp8_f32(f0, f1, v, false);
    v = __builtin_amdgcn_cvt_pk_fp8_f32(f2, f3, v, true);
    return (unsigned)v;
}

// xpad layout (fp8): [b][yy(144)][xx(144)][64 B: byte i = ch i (plain order)]
#define XROWB  9216
#define XBATCH 1327104
#define USCALE 256.0f

// ---------------- prep2: c2 + xpad + pad + U + W2s + V + hcp (one grid) -----
__global__ void prep2(const float* __restrict__ x,  const float* __restrict__ pk,
                      const float* __restrict__ W1, const float* __restrict__ W2,
                      const float* __restrict__ b1,
                      const float* __restrict__ c,
                      const float* __restrict__ Wv, const float* __restrict__ bv,
                      const float* __restrict__ Wo, const float* __restrict__ bo,
                      const float* __restrict__ lng, const float* __restrict__ lnb,
                      unsigned char* __restrict__ xp, unsigned char* __restrict__ Uf,
                      unsigned short* __restrict__ W2s,
                      float* __restrict__ V, float* __restrict__ hcp,
                      float* __restrict__ outc2)
{
    const int blk = blockIdx.x, tid = threadIdx.x;
    __shared__ float sc[512], sv[512], c2s[512];

    if (blk >= 667) {
        // ---- in-block c2: each 64-lane wave handles one batch ----
        sc[tid] = c[tid]; sc[tid + 256] = c[tid + 256];
        __syncthreads();
        #pragma unroll
        for (int half = 0; half < 2; ++half) {
            int it = tid + half*256;
            int bb = it >> 6, j = it & 63;
            float v = bv[j];
            for (int i = 0; i < 64; ++i) v += sc[bb*64 + i]*Wv[i*64 + j];
            sv[it] = v;
        }
        __syncthreads();
        #pragma unroll
        for (int half = 0; half < 2; ++half) {
            int it = tid + half*256;
            int bb = it >> 6, j = it & 63;
            float t = bo[j] + sc[it];
            for (int i = 0; i < 64; ++i) t += sv[bb*64 + i]*Wo[i*64 + j];
            float s = t;
            for (int o = 32; o > 0; o >>= 1) s += __shfl_xor(s, o);
            float m = s * (1.f/64.f);
            float dq = (t - m)*(t - m);
            for (int o = 32; o > 0; o >>= 1) dq += __shfl_xor(dq, o);
            float a = (t - m) / sqrtf(dq*(1.f/64.f) + 1e-5f) * lng[j] + lnb[j];
            c2s[it] = sc[it] + a;
        }
        __syncthreads();
    }

    if (blk < 512) {
        // convert: 16 lanes per px; one float4 load + one dword store per iter.
        // wave = 4 px: load 1024 B contiguous, store 256 B contiguous.
        const int ci = tid & 15;
        #pragma unroll 4
        for (int it = 0; it < 16; ++it) {
            int px = blk*256 + it*16 + (tid >> 4);
            int xc = px & 127, y = (px >> 7) & 127, b = px >> 14;
            float4 f = *(const float4*)(x + (size_t)px*64 + ci*4);
            unsigned P = pk4fp8(f.x, f.y, f.z, f.w);
            *(unsigned*)(xp + (size_t)b*XBATCH + (size_t)(y+8)*XROWB
                            + (size_t)(xc+8)*64 + ci*4) = P;
        }
    } else if (blk < 648) {
        int idx = (blk - 512)*256 + tid;     // [0,34816) pad px
        int b = idx / 4352, r = idx - b*4352;
        int yy, xx;
        if (r < 2304) { int ry = r / 144; xx = r - ry*144; yy = (ry < 8) ? ry : 128 + ry; }
        else { int r2 = r - 2304; yy = 8 + (r2 >> 4); int xi = r2 & 15; xx = (xi < 8) ? xi : 128 + xi; }
        unsigned char* d = xp + (size_t)b*XBATCH + (size_t)yy*XROWB + (size_t)xx*64;
        uint4 z = make_uint4(0,0,0,0);
        *(uint4*)(d) = z; *(uint4*)(d+16) = z; *(uint4*)(d+32) = z; *(uint4*)(d+48) = z;
    } else if (blk < 665) {
        // U frags for 32x32x64 f8f6f4: entry (pos, nt, lane) = 32 B
        // layout: Uf + pos*4096 + nt*2048 + lane*16  (+1024 for k-bytes 16..31)
        int idx = (blk - 648)*256 + tid;     // [0, 4224) = 33*2*64
        if (idx < 4224) {
            int lane = idx & 63, nt = (idx >> 6) & 1, pos = idx >> 7;
            int n  = nt*32 + (lane & 31);
            int h  = lane >> 5;              // k-group: ch h*32 .. h*32+31
            static constexpr int DI[33] = {3,3,3, 2,2,2, 1,1,1, 0,0,0, -1, 0,0, 1,1, 2,2, 3,3,
                                           0,0,0, 1,1,1, 2,2,2, 3,3,3};
            static constexpr int TT[33] = {0,1,2, 0,1,2, 0,1,2, 0,1,2, 4, 3,5, 3,5, 3,5, 3,5,
                                           6,7,8, 6,7,8, 6,7,8, 6,7,8};
            int di = DI[pos], t = TT[pos];
            float vv[32];
            #pragma unroll
            for (int j = 0; j < 32; ++j) {
                int ch = h*32 + j;
                float v;
                if (di < 0) {               // merged center
                    v = W1[ch*64 + n];
                    for (int dd = 0; dd < 4; ++dd)
                        v += pk[(dd*128 + ch)*9 + 4] * W1[((1+dd)*128 + ch)*64 + n];
                } else {
                    v = pk[(di*128 + ch)*9 + t] * W1[((1+di)*128 + ch)*64 + n];
                }
                vv[j] = v * USCALE;
            }
            unsigned char* base = Uf + (size_t)pos*4096 + nt*2048 + lane*16;
            uint4 o0, o1;
            o0.x = pk4fp8(vv[0],  vv[1],  vv[2],  vv[3]);
            o0.y = pk4fp8(vv[4],  vv[5],  vv[6],  vv[7]);
            o0.z = pk4fp8(vv[8],  vv[9],  vv[10], vv[11]);
            o0.w = pk4fp8(vv[12], vv[13], vv[14], vv[15]);
            o1.x = pk4fp8(vv[16], vv[17], vv[18], vv[19]);
            o1.y = pk4fp8(vv[20], vv[21], vv[22], vv[23]);
            o1.z = pk4fp8(vv[24], vv[25], vv[26], vv[27]);
            o1.w = pk4fp8(vv[28], vv[29], vv[30], vv[31]);
            *(uint4*)(base)        = o0;
            *(uint4*)(base + 1024) = o1;
        }
    } else if (blk < 667) {
        int idx = (blk - 665)*256 + tid;     // [0,512)
        int lane = idx & 63, nt = (idx >> 6) & 3, kc2 = (idx >> 8) & 1;
        int n  = nt*16 + (lane & 15);
        int k0 = kc2*32 + (lane >> 4)*8;
        unsigned short e[8];
        #pragma unroll
        for (int j = 0; j < 8; ++j) e[j] = f2bf(W2[(k0+j)*64 + n]);
        uint4 o;
        o.x = (unsigned)e[0] | ((unsigned)e[1] << 16);
        o.y = (unsigned)e[2] | ((unsigned)e[3] << 16);
        o.z = (unsigned)e[4] | ((unsigned)e[5] << 16);
        o.w = (unsigned)e[6] | ((unsigned)e[7] << 16);
        *(uint4*)(W2s + (size_t)idx*8) = o;
    } else if (blk < 739) {
        int idx = (blk - 667)*256 + tid;     // [0, 18432) = 8*36*64
        int n = idx & 63, q = idx >> 6;
        int p = q % 36, b = q / 36;
        int di = p/9, t = p%9;
        float s = 0.f;
        for (int j = 0; j < 64; ++j)
            s += c2s[b*64 + j] * pk[(di*128 + 64 + j)*9 + t] * W1[((1+di)*128 + 64 + j)*64 + n];
        V[(size_t)q*64 + n] = s;
    } else {
        for (int it = tid; it < 512; it += 256) {
            int b = it >> 6, n = it & 63;
            float s = b1[n];
            for (int j = 0; j < 64; ++j) s += c2s[b*64 + j]*W1[(64 + j)*64 + n];
            hcp[it] = s;
            outc2[it] = c2s[it];
        }
    }
}

// ---------------- main fused kernel -----------------------------------------
#define HID_S 72

__global__ __launch_bounds__(512, 4) void nca_main(
    const unsigned char* __restrict__ xp,
    const unsigned char* __restrict__ U,
    const unsigned short* __restrict__ W2s,
    const float* __restrict__ V,
    const float* __restrict__ hcp,
    const float* __restrict__ b2,
    float* __restrict__ out)
{
    // smem: during K-loop = U double-buffer (2 x 32768); after = hid 256*72*2
    __shared__ __align__(16) unsigned char smem[65536];
    __shared__ float V_l[36*64];              //  9216 B
    __shared__ float Cx_l[16*64];             //  4096 B
    __shared__ float Cy_l[2*64];              //   512 B
    __shared__ float hc2_l[64];               //   256 B  -> 79,616 B total

    unsigned short* hid = (unsigned short*)smem;

    const int tid = threadIdx.x;
    const int blk = blockIdx.x;
    const int b  = blk & 7;                   // XCD-local batch (512 % 8 == 0)
    const int y0 = (blk >> 3) * 2;            // two rows per block

    // ---- stage K-block 0 (pos 0..7, 32 KB) into buffer 0 (DMA, async) ----
    #pragma unroll
    for (int s = 0; s < 4; ++s) {
        int off = tid*16 + s*8192;
        __builtin_amdgcn_global_load_lds(
            (const __attribute__((address_space(1))) unsigned int*)(U + off),
            (__attribute__((address_space(3))) unsigned int*)(smem + off),
            16, 0, 0);
    }

    // ---- tables ----
    {
        const float4* Vg = (const float4*)(V + (size_t)b*2304);
        for (int i = tid; i < 576; i += 512) ((float4*)V_l)[i] = Vg[i];
    }
    __syncthreads();
    for (int it = tid; it < 1024; it += 512) {      // Cx: x-edge correction
        int xi = it >> 6, n = it & 63;
        int xx = xi < 8 ? xi : 112 + xi;
        float s = 0.f;
        #pragma unroll
        for (int di = 0; di < 4; ++di) {
            int d = 1 << di;
            int dxo = (xx < d) ? 0 : ((xx >= 128 - d) ? 2 : -1);
            if (dxo >= 0) {
                s += V_l[(di*9 + 0*3 + dxo)*64 + n];
                s += V_l[(di*9 + 1*3 + dxo)*64 + n];
                s += V_l[(di*9 + 2*3 + dxo)*64 + n];
            }
        }
        Cx_l[it] = s;
    }
    if (tid < 128) {                                // Cy for this block's 2 rows
        int r = tid >> 6, n = tid & 63;
        int yy = y0 + r;
        float s = 0.f;
        #pragma unroll
        for (int di = 0; di < 4; ++di) {
            int d = 1 << di;
            int dyo = (yy < d) ? 0 : ((yy >= 128 - d) ? 2 : -1);
            if (dyo >= 0) {
                s += V_l[(di*9 + dyo*3 + 0)*64 + n];
                s += V_l[(di*9 + dyo*3 + 1)*64 + n];
                s += V_l[(di*9 + dyo*3 + 2)*64 + n];
            }
        }
        Cy_l[tid] = s;
    } else if (tid < 192) {
        int n = tid - 128;
        float s = hcp[b*64 + n];
        for (int p = 0; p < 36; ++p) s += V_l[p*64 + n];
        hc2_l[n] = s;
    }
    __syncthreads();   // publishes U K-block 0 (vmcnt drained) + tables

    // ---- geometry: wave w -> row y0+(w>>2), x in [(w&3)*32, +32) ----
    const int lane = tid & 63;
    const int w    = tid >> 6;
    const int rib  = w >> 2;                  // row in block
    const int y    = y0 + rib;
    const int xw   = (w & 3) * 32;
    const int ln15 = lane & 15;
    const int oct  = lane >> 4;
    const int l31  = lane & 31;
    const int kg   = lane >> 5;               // k-group for 32x32x64

    // A: 32 contiguous bytes (ch kg*32 .. +31) of px (xw + l31)
    const unsigned char* abase = xp + (size_t)b*XBATCH + (size_t)(y + 8)*XROWB
                               + (size_t)(xw + l31 + 8)*64 + kg*32;

    f32x16 acc[2];
    #pragma unroll
    for (int nt = 0; nt < 2; ++nt)
        #pragma unroll
        for (int r = 0; r < 16; ++r) acc[nt][r] = 0.f;

    // byte offsets (px stride 64 B), order matches prep2 U pos order
    static constexpr int OFF[33] = {
        (-8*144-8)*64, (-8*144)*64, (-8*144+8)*64,
        (-4*144-4)*64, (-4*144)*64, (-4*144+4)*64,
        (-2*144-2)*64, (-2*144)*64, (-2*144+2)*64,
        (-1*144-1)*64, (-1*144)*64, (-1*144+1)*64,
        0,
        -64, 64, -128, 128, -256, 256, -512, 512,
        ( 1*144-1)*64, ( 1*144)*64, ( 1*144+1)*64,
        ( 2*144-2)*64, ( 2*144)*64, ( 2*144+2)*64,
        ( 4*144-4)*64, ( 4*144)*64, ( 4*144+4)*64,
        ( 8*144-8)*64, ( 8*144)*64, ( 8*144+8)*64
    };

    auto loadB = [&](int cofs, int p, i32x8* Bv) {
        const unsigned char* rp = smem + cofs + p*4096 + lane*16;
        #pragma unroll
        for (int nt = 0; nt < 2; ++nt) {
            i32x4 lo = *(const i32x4*)(rp + nt*2048);
            i32x4 hi = *(const i32x4*)(rp + nt*2048 + 1024);
            i32x8 v;
            v[0]=lo[0]; v[1]=lo[1]; v[2]=lo[2]; v[3]=lo[3];
            v[4]=hi[0]; v[5]=hi[1]; v[6]=hi[2]; v[7]=hi[3];
            Bv[nt] = v;
        }
    };

    // K-loop: 4 K-blocks of 8 positions + tail pos 32. One barrier per K-block.
    i32x8 Areg[2];
    i32x8 Breg[2][2];
    Areg[0] = *(const i32x8*)(abase + OFF[0]);
    loadB(0, 0, Breg[0]);

    int cur = 0;
    #pragma unroll 1
    for (int kb = 0; kb < 4; ++kb) {
        {   // stage next K-block into the other buffer (DMA, linear layout)
            const int nbytes = (kb < 3) ? 32768 : 4096;
            const unsigned char* gsrc = U + (size_t)(kb + 1)*32768;
            unsigned char* ldst = smem + (cur ^ 1)*32768;
            for (int off = tid*16; off < nbytes; off += 8192)
                __builtin_amdgcn_global_load_lds(
                    (const __attribute__((address_space(1))) unsigned int*)(gsrc + off),
                    (__attribute__((address_space(3))) unsigned int*)(ldst + off),
                    16, 0, 0);
        }
        const int cofs = cur*32768;
        #pragma unroll
        for (int p = 0; p < 8; ++p) {
            const int pos = kb*8 + p;
            Areg[(p + 1) & 1] = *(const i32x8*)(abase + OFF[pos + 1]); // dist-1
            if (p < 7) loadB(cofs, p + 1, Breg[(p + 1) & 1]);          // dist-1
            __builtin_amdgcn_s_setprio(1);
            acc[0] = __builtin_amdgcn_mfma_scale_f32_32x32x64_f8f6f4(
                Areg[p & 1], Breg[p & 1][0], acc[0], 0, 0, 0, 0x7F7F7F7F, 0, 0x7F7F7F7F);
            acc[1] = __builtin_amdgcn_mfma_scale_f32_32x32x64_f8f6f4(
                Areg[p & 1], Breg[p & 1][1], acc[1], 0, 0, 0, 0x7F7F7F7F, 0, 0x7F7F7F7F);
            __builtin_amdgcn_s_setprio(0);
        }
        __syncthreads();          // drains this wave's DMA + publishes buffer
        cur ^= 1;
        loadB(cur*32768, 0, Breg[0]);                  // first B of next block
    }
    // tail: pos 32 (Areg[0] prefetched at kb=3,p=7; Breg[0] just loaded)
    __builtin_amdgcn_s_setprio(1);
    acc[0] = __builtin_amdgcn_mfma_scale_f32_32x32x64_f8f6f4(
        Areg[0], Breg[0][0], acc[0], 0, 0, 0, 0x7F7F7F7F, 0, 0x7F7F7F7F);
    acc[1] = __builtin_amdgcn_mfma_scale_f32_32x32x64_f8f6f4(
        Areg[0], Breg[0][1], acc[1], 0, 0, 0, 0x7F7F7F7F, 0, 0x7F7F7F7F);
    __builtin_amdgcn_s_setprio(0);
    __syncthreads();              // all U reads done -> safe to overwrite as hid

    // ---- epilogue 1: acc/256 + hc2 - corrections, GELU, write hid (bf16) ----
    // 32x32 C/D layout: col = lane&31, row = (reg&3) + 8*(reg>>2) + 4*(lane>>5)
    const bool yedge = (y < 8) || (y >= 120);
    #pragma unroll
    for (int nt = 0; nt < 2; ++nt) {
        const int n = nt*32 + l31;
        const float hcv = hc2_l[n];
        const float cyv = yedge ? Cy_l[rib*64 + n] : 0.f;
        #pragma unroll
        for (int reg = 0; reg < 16; ++reg) {
            int row = (reg & 3) + 8*(reg >> 2) + 4*kg;
            int x = xw + row;
            float h = acc[nt][reg]*(1.0f/USCALE) + hcv - cyv;
            if (x < 8 || x >= 120) {
                int xi = (x < 8) ? x : (x - 112);
                h -= Cx_l[xi*64 + n];
                if (yedge) {                    // corner double-subtract fix
                    #pragma unroll
                    for (int di = 0; di < 4; ++di) {
                        int d = 1 << di;
                        int dyo = (y < d) ? 0 : ((y >= 128 - d) ? 2 : -1);
                        int dxo = (x < d) ? 0 : ((x >= 128 - d) ? 2 : -1);
                        if (dyo >= 0 && dxo >= 0)
                            h += V_l[(di*9 + dyo*3 + dxo)*64 + n];
                    }
                }
            }
            float u = 0.7978845608028654f * (h + 0.044715f*h*h*h);
            float g = h / (1.f + __expf(-2.f*u));
            hid[(rib*128 + x)*HID_S + n] = f2bf(g);
        }
    }
    // each wave reads back only its own 32 hid rows -> no barrier needed

    // ---- GEMM2: y = hid @ W2 + b2 (bf16, 16x16x32) ----
    f32x4 acc2[2][4];
    #pragma unroll
    for (int mt = 0; mt < 2; ++mt)
        #pragma unroll
        for (int nt = 0; nt < 4; ++nt) {
            acc2[mt][nt][0] = 0.f; acc2[mt][nt][1] = 0.f;
            acc2[mt][nt][2] = 0.f; acc2[mt][nt][3] = 0.f;
        }
    #pragma unroll
    for (int kc2 = 0; kc2 < 2; ++kc2) {
        s16x8 a2[2];
        #pragma unroll
        for (int mt = 0; mt < 2; ++mt)
            a2[mt] = *(const s16x8*)&hid[(rib*128 + xw + mt*16 + ln15)*HID_S + kc2*32 + oct*8];
        #pragma unroll
        for (int nt = 0; nt < 4; ++nt) {
            s16x8 bfr = *(const s16x8*)(W2s + ((size_t)(kc2*4 + nt)*64 + lane)*8);
            #pragma unroll
            for (int mt = 0; mt < 2; ++mt)
                acc2[mt][nt] = __builtin_amdgcn_mfma_f32_16x16x32_bf16(a2[mt], bfr, acc2[mt][nt], 0, 0, 0);
        }
    }

    float* ob = out + ((size_t)(b*128 + y))*128*64;
    #pragma unroll
    for (int nt = 0; nt < 4; ++nt) {
        const float b2v = b2[nt*16 + ln15];
        #pragma unroll
        for (int mt = 0; mt < 2; ++mt) {
            #pragma unroll
            for (int r = 0; r < 4; ++r) {
                int x = xw + mt*16 + oct*4 + r;
                ob[(size_t)x*64 + nt*16 + ln15] = acc2[mt][nt][r] + b2v;
            }
        }
    }
}

// ---------------- launch ----------------------------------------------------
extern "C" void kernel_launch(void* const* d_in, const int* in_sizes, int n_in,
                              void* d_out, int out_size, void* d_ws, size_t ws_size,
                              hipStream_t stream) {
    const float* x   = (const float*)d_in[0];
    const float* c   = (const float*)d_in[1];
    // d_in[2..5] = Wq,bq,Wk,bk : unused (softmax weights sum to 1 -> pool == v)
    const float* Wv  = (const float*)d_in[6];
    const float* bv  = (const float*)d_in[7];
    const float* Wo  = (const float*)d_in[8];
    const float* bo  = (const float*)d_in[9];
    const float* lng = (const float*)d_in[10];
    const float* lnb = (const float*)d_in[11];
    const float* pk  = (const float*)d_in[12];
    const float* W1  = (const float*)d_in[13];
    const float* b1  = (const float*)d_in[14];
    const float* W2  = (const float*)d_in[15];
    const float* b2  = (const float*)d_in[16];
    float* out = (float*)d_out;

    char* w = (char*)d_ws;
    unsigned char*  xpb = (unsigned char*)(w);                   // 10,616,832 B
    unsigned char*  Uf  = (unsigned char*)(w + 10616832);        //    135,168 B
    unsigned short* W2s = (unsigned short*)(w + 10752000);       //      8,192 B
    float*          V   = (float*)         (w + 10760192);       //     73,728 B
    float*          hcp = (float*)         (w + 10833920);       //      2,048 B (end 10,835,968)

    prep2<<<740, 256, 0, stream>>>(x, pk, W1, W2, b1, c, Wv, bv, Wo, bo, lng, lnb,
                                   xpb, Uf, W2s, V, hcp, out + 8388608);
    nca_main<<<512, 512, 0, stream>>>(xpb, Uf, W2s, V, hcp, b2, out);
}

// Round 4
// 149.970 us; speedup vs baseline: 1.1114x; 1.0021x over previous
//
#include <hip/hip_runtime.h>
#include <hip/hip_bf16.h>
#include <math.h>

// B=8, H=W=128, CH=64, OC=64, NCA_C=128, K=3, dils {1,2,4,8}, HID=64
// out: y [8,128,128,64] fp32 (8388608) then c2 [8,64] fp32 (512)
//
// Depthwise conv folded into GEMM1 over 33 positions (center-merged), fp8-e4m3
// (U scaled x256), MX-scaled mfma_scale_f32_32x32x64_f8f6f4 (unit E8M0 scales).
// Round-13: A-prefetch distance 3.
//  - Round-12 post-mortem: MX halved MFMA-pipe time (17->7.6us) but wall moved
//    only -4us: per-pos MFMA work dropped to ~34 cyc/wave (~136 cyc/SIMD at 4
//    waves) while the dist-1 A prefetch gives only ~136 cyc slack vs ~200-400
//    cyc L2 latency (block footprint 101 KB >> 32 KB L1) -> A-latency chain.
//  - Now: 4 A register buffers, prefetch distance 3 (~408 cyc slack >= L2
//    latency). +16 VGPR, still <=128 for 4 waves/SIMD. B stays dist-1 (LDS
//    latency ~120 cyc < 136 cyc slack).
//  - K-block = 8 positions (32 KB x2 LDS double-buffer), 5 barriers total.
// NO register rotation copies anywhere (compile-time parity ping-pong).

typedef float  f32x4  __attribute__((ext_vector_type(4)));
typedef float  f32x16 __attribute__((ext_vector_type(16)));
typedef short  s16x8  __attribute__((ext_vector_type(8)));
typedef int    i32x4  __attribute__((ext_vector_type(4)));
typedef int    i32x8  __attribute__((ext_vector_type(8)));

static __device__ __forceinline__ unsigned short f2bf(float f) {
    __hip_bfloat16 h = __float2bfloat16(f);
    unsigned short u; __builtin_memcpy(&u, &h, 2); return u;
}
static __device__ __forceinline__ unsigned pk4fp8(float f0, float f1, float f2, float f3) {
    int v = 0;
    v = __builtin_amdgcn_cvt_pk_fp8_f32(f0, f1, v, false);
    v = __builtin_amdgcn_cvt_pk_fp8_f32(f2, f3, v, true);
    return (unsigned)v;
}

// xpad layout (fp8): [b][yy(144)][xx(144)][64 B: byte i = ch i (plain order)]
#define XROWB  9216
#define XBATCH 1327104
#define USCALE 256.0f

// ---------------- prep2: c2 + xpad + pad + U + W2s + V + hcp (one grid) -----
__global__ void prep2(const float* __restrict__ x,  const float* __restrict__ pk,
                      const float* __restrict__ W1, const float* __restrict__ W2,
                      const float* __restrict__ b1,
                      const float* __restrict__ c,
                      const float* __restrict__ Wv, const float* __restrict__ bv,
                      const float* __restrict__ Wo, const float* __restrict__ bo,
                      const float* __restrict__ lng, const float* __restrict__ lnb,
                      unsigned char* __restrict__ xp, unsigned char* __restrict__ Uf,
                      unsigned short* __restrict__ W2s,
                      float* __restrict__ V, float* __restrict__ hcp,
                      float* __restrict__ outc2)
{
    const int blk = blockIdx.x, tid = threadIdx.x;
    __shared__ float sc[512], sv[512], c2s[512];

    if (blk >= 667) {
        // ---- in-block c2: each 64-lane wave handles one batch ----
        sc[tid] = c[tid]; sc[tid + 256] = c[tid + 256];
        __syncthreads();
        #pragma unroll
        for (int half = 0; half < 2; ++half) {
            int it = tid + half*256;
            int bb = it >> 6, j = it & 63;
            float v = bv[j];
            for (int i = 0; i < 64; ++i) v += sc[bb*64 + i]*Wv[i*64 + j];
            sv[it] = v;
        }
        __syncthreads();
        #pragma unroll
        for (int half = 0; half < 2; ++half) {
            int it = tid + half*256;
            int bb = it >> 6, j = it & 63;
            float t = bo[j] + sc[it];
            for (int i = 0; i < 64; ++i) t += sv[bb*64 + i]*Wo[i*64 + j];
            float s = t;
            for (int o = 32; o > 0; o >>= 1) s += __shfl_xor(s, o);
            float m = s * (1.f/64.f);
            float dq = (t - m)*(t - m);
            for (int o = 32; o > 0; o >>= 1) dq += __shfl_xor(dq, o);
            float a = (t - m) / sqrtf(dq*(1.f/64.f) + 1e-5f) * lng[j] + lnb[j];
            c2s[it] = sc[it] + a;
        }
        __syncthreads();
    }

    if (blk < 512) {
        // convert: 16 lanes per px; one float4 load + one dword store per iter.
        // wave = 4 px: load 1024 B contiguous, store 256 B contiguous.
        const int ci = tid & 15;
        #pragma unroll 4
        for (int it = 0; it < 16; ++it) {
            int px = blk*256 + it*16 + (tid >> 4);
            int xc = px & 127, y = (px >> 7) & 127, b = px >> 14;
            float4 f = *(const float4*)(x + (size_t)px*64 + ci*4);
            unsigned P = pk4fp8(f.x, f.y, f.z, f.w);
            *(unsigned*)(xp + (size_t)b*XBATCH + (size_t)(y+8)*XROWB
                            + (size_t)(xc+8)*64 + ci*4) = P;
        }
    } else if (blk < 648) {
        int idx = (blk - 512)*256 + tid;     // [0,34816) pad px
        int b = idx / 4352, r = idx - b*4352;
        int yy, xx;
        if (r < 2304) { int ry = r / 144; xx = r - ry*144; yy = (ry < 8) ? ry : 128 + ry; }
        else { int r2 = r - 2304; yy = 8 + (r2 >> 4); int xi = r2 & 15; xx = (xi < 8) ? xi : 128 + xi; }
        unsigned char* d = xp + (size_t)b*XBATCH + (size_t)yy*XROWB + (size_t)xx*64;
        uint4 z = make_uint4(0,0,0,0);
        *(uint4*)(d) = z; *(uint4*)(d+16) = z; *(uint4*)(d+32) = z; *(uint4*)(d+48) = z;
    } else if (blk < 665) {
        // U frags for 32x32x64 f8f6f4: entry (pos, nt, lane) = 32 B
        // layout: Uf + pos*4096 + nt*2048 + lane*16  (+1024 for k-bytes 16..31)
        int idx = (blk - 648)*256 + tid;     // [0, 4224) = 33*2*64
        if (idx < 4224) {
            int lane = idx & 63, nt = (idx >> 6) & 1, pos = idx >> 7;
            int n  = nt*32 + (lane & 31);
            int h  = lane >> 5;              // k-group: ch h*32 .. h*32+31
            static constexpr int DI[33] = {3,3,3, 2,2,2, 1,1,1, 0,0,0, -1, 0,0, 1,1, 2,2, 3,3,
                                           0,0,0, 1,1,1, 2,2,2, 3,3,3};
            static constexpr int TT[33] = {0,1,2, 0,1,2, 0,1,2, 0,1,2, 4, 3,5, 3,5, 3,5, 3,5,
                                           6,7,8, 6,7,8, 6,7,8, 6,7,8};
            int di = DI[pos], t = TT[pos];
            float vv[32];
            #pragma unroll
            for (int j = 0; j < 32; ++j) {
                int ch = h*32 + j;
                float v;
                if (di < 0) {               // merged center
                    v = W1[ch*64 + n];
                    for (int dd = 0; dd < 4; ++dd)
                        v += pk[(dd*128 + ch)*9 + 4] * W1[((1+dd)*128 + ch)*64 + n];
                } else {
                    v = pk[(di*128 + ch)*9 + t] * W1[((1+di)*128 + ch)*64 + n];
                }
                vv[j] = v * USCALE;
            }
            unsigned char* base = Uf + (size_t)pos*4096 + nt*2048 + lane*16;
            uint4 o0, o1;
            o0.x = pk4fp8(vv[0],  vv[1],  vv[2],  vv[3]);
            o0.y = pk4fp8(vv[4],  vv[5],  vv[6],  vv[7]);
            o0.z = pk4fp8(vv[8],  vv[9],  vv[10], vv[11]);
            o0.w = pk4fp8(vv[12], vv[13], vv[14], vv[15]);
            o1.x = pk4fp8(vv[16], vv[17], vv[18], vv[19]);
            o1.y = pk4fp8(vv[20], vv[21], vv[22], vv[23]);
            o1.z = pk4fp8(vv[24], vv[25], vv[26], vv[27]);
            o1.w = pk4fp8(vv[28], vv[29], vv[30], vv[31]);
            *(uint4*)(base)        = o0;
            *(uint4*)(base + 1024) = o1;
        }
    } else if (blk < 667) {
        int idx = (blk - 665)*256 + tid;     // [0,512)
        int lane = idx & 63, nt = (idx >> 6) & 3, kc2 = (idx >> 8) & 1;
        int n  = nt*16 + (lane & 15);
        int k0 = kc2*32 + (lane >> 4)*8;
        unsigned short e[8];
        #pragma unroll
        for (int j = 0; j < 8; ++j) e[j] = f2bf(W2[(k0+j)*64 + n]);
        uint4 o;
        o.x = (unsigned)e[0] | ((unsigned)e[1] << 16);
        o.y = (unsigned)e[2] | ((unsigned)e[3] << 16);
        o.z = (unsigned)e[4] | ((unsigned)e[5] << 16);
        o.w = (unsigned)e[6] | ((unsigned)e[7] << 16);
        *(uint4*)(W2s + (size_t)idx*8) = o;
    } else if (blk < 739) {
        int idx = (blk - 667)*256 + tid;     // [0, 18432) = 8*36*64
        int n = idx & 63, q = idx >> 6;
        int p = q % 36, b = q / 36;
        int di = p/9, t = p%9;
        float s = 0.f;
        for (int j = 0; j < 64; ++j)
            s += c2s[b*64 + j] * pk[(di*128 + 64 + j)*9 + t] * W1[((1+di)*128 + 64 + j)*64 + n];
        V[(size_t)q*64 + n] = s;
    } else {
        for (int it = tid; it < 512; it += 256) {
            int b = it >> 6, n = it & 63;
            float s = b1[n];
            for (int j = 0; j < 64; ++j) s += c2s[b*64 + j]*W1[(64 + j)*64 + n];
            hcp[it] = s;
            outc2[it] = c2s[it];
        }
    }
}

// ---------------- main fused kernel -----------------------------------------
#define HID_S 72

__global__ __launch_bounds__(512, 4) void nca_main(
    const unsigned char* __restrict__ xp,
    const unsigned char* __restrict__ U,
    const unsigned short* __restrict__ W2s,
    const float* __restrict__ V,
    const float* __restrict__ hcp,
    const float* __restrict__ b2,
    float* __restrict__ out)
{
    // smem: during K-loop = U double-buffer (2 x 32768); after = hid 256*72*2
    __shared__ __align__(16) unsigned char smem[65536];
    __shared__ float V_l[36*64];              //  9216 B
    __shared__ float Cx_l[16*64];             //  4096 B
    __shared__ float Cy_l[2*64];              //   512 B
    __shared__ float hc2_l[64];               //   256 B  -> 79,616 B total

    unsigned short* hid = (unsigned short*)smem;

    const int tid = threadIdx.x;
    const int blk = blockIdx.x;
    const int b  = blk & 7;                   // XCD-local batch (512 % 8 == 0)
    const int y0 = (blk >> 3) * 2;            // two rows per block

    // ---- stage K-block 0 (pos 0..7, 32 KB) into buffer 0 (DMA, async) ----
    #pragma unroll
    for (int s = 0; s < 4; ++s) {
        int off = tid*16 + s*8192;
        __builtin_amdgcn_global_load_lds(
            (const __attribute__((address_space(1))) unsigned int*)(U + off),
            (__attribute__((address_space(3))) unsigned int*)(smem + off),
            16, 0, 0);
    }

    // ---- tables ----
    {
        const float4* Vg = (const float4*)(V + (size_t)b*2304);
        for (int i = tid; i < 576; i += 512) ((float4*)V_l)[i] = Vg[i];
    }
    __syncthreads();
    for (int it = tid; it < 1024; it += 512) {      // Cx: x-edge correction
        int xi = it >> 6, n = it & 63;
        int xx = xi < 8 ? xi : 112 + xi;
        float s = 0.f;
        #pragma unroll
        for (int di = 0; di < 4; ++di) {
            int d = 1 << di;
            int dxo = (xx < d) ? 0 : ((xx >= 128 - d) ? 2 : -1);
            if (dxo >= 0) {
                s += V_l[(di*9 + 0*3 + dxo)*64 + n];
                s += V_l[(di*9 + 1*3 + dxo)*64 + n];
                s += V_l[(di*9 + 2*3 + dxo)*64 + n];
            }
        }
        Cx_l[it] = s;
    }
    if (tid < 128) {                                // Cy for this block's 2 rows
        int r = tid >> 6, n = tid & 63;
        int yy = y0 + r;
        float s = 0.f;
        #pragma unroll
        for (int di = 0; di < 4; ++di) {
            int d = 1 << di;
            int dyo = (yy < d) ? 0 : ((yy >= 128 - d) ? 2 : -1);
            if (dyo >= 0) {
                s += V_l[(di*9 + dyo*3 + 0)*64 + n];
                s += V_l[(di*9 + dyo*3 + 1)*64 + n];
                s += V_l[(di*9 + dyo*3 + 2)*64 + n];
            }
        }
        Cy_l[tid] = s;
    } else if (tid < 192) {
        int n = tid - 128;
        float s = hcp[b*64 + n];
        for (int p = 0; p < 36; ++p) s += V_l[p*64 + n];
        hc2_l[n] = s;
    }
    __syncthreads();   // publishes U K-block 0 (vmcnt drained) + tables

    // ---- geometry: wave w -> row y0+(w>>2), x in [(w&3)*32, +32) ----
    const int lane = tid & 63;
    const int w    = tid >> 6;
    const int rib  = w >> 2;                  // row in block
    const int y    = y0 + rib;
    const int xw   = (w & 3) * 32;
    const int ln15 = lane & 15;
    const int oct  = lane >> 4;
    const int l31  = lane & 31;
    const int kg   = lane >> 5;               // k-group for 32x32x64

    // A: 32 contiguous bytes (ch kg*32 .. +31) of px (xw + l31)
    const unsigned char* abase = xp + (size_t)b*XBATCH + (size_t)(y + 8)*XROWB
                               + (size_t)(xw + l31 + 8)*64 + kg*32;

    f32x16 acc[2];
    #pragma unroll
    for (int nt = 0; nt < 2; ++nt)
        #pragma unroll
        for (int r = 0; r < 16; ++r) acc[nt][r] = 0.f;

    // byte offsets (px stride 64 B), order matches prep2 U pos order
    static constexpr int OFF[33] = {
        (-8*144-8)*64, (-8*144)*64, (-8*144+8)*64,
        (-4*144-4)*64, (-4*144)*64, (-4*144+4)*64,
        (-2*144-2)*64, (-2*144)*64, (-2*144+2)*64,
        (-1*144-1)*64, (-1*144)*64, (-1*144+1)*64,
        0,
        -64, 64, -128, 128, -256, 256, -512, 512,
        ( 1*144-1)*64, ( 1*144)*64, ( 1*144+1)*64,
        ( 2*144-2)*64, ( 2*144)*64, ( 2*144+2)*64,
        ( 4*144-4)*64, ( 4*144)*64, ( 4*144+4)*64,
        ( 8*144-8)*64, ( 8*144)*64, ( 8*144+8)*64
    };

    auto loadB = [&](int cofs, int p, i32x8* Bv) {
        const unsigned char* rp = smem + cofs + p*4096 + lane*16;
        #pragma unroll
        for (int nt = 0; nt < 2; ++nt) {
            i32x4 lo = *(const i32x4*)(rp + nt*2048);
            i32x4 hi = *(const i32x4*)(rp + nt*2048 + 1024);
            i32x8 v;
            v[0]=lo[0]; v[1]=lo[1]; v[2]=lo[2]; v[3]=lo[3];
            v[4]=hi[0]; v[5]=hi[1]; v[6]=hi[2]; v[7]=hi[3];
            Bv[nt] = v;
        }
    };

    // K-loop: 4 K-blocks of 8 positions + tail pos 32. One barrier per K-block.
    // A register ring of 4, prefetch distance 3 (covers ~300-400 cyc L2 latency;
    // dist-1 left only ~136 cyc of slack once MX halved per-pos MFMA work).
    i32x8 Areg[4];
    i32x8 Breg[2][2];
    Areg[0] = *(const i32x8*)(abase + OFF[0]);
    Areg[1] = *(const i32x8*)(abase + OFF[1]);
    Areg[2] = *(const i32x8*)(abase + OFF[2]);
    loadB(0, 0, Breg[0]);

    int cur = 0;
    #pragma unroll 1
    for (int kb = 0; kb < 4; ++kb) {
        {   // stage next K-block into the other buffer (DMA, linear layout)
            const int nbytes = (kb < 3) ? 32768 : 4096;
            const unsigned char* gsrc = U + (size_t)(kb + 1)*32768;
            unsigned char* ldst = smem + (cur ^ 1)*32768;
            for (int off = tid*16; off < nbytes; off += 8192)
                __builtin_amdgcn_global_load_lds(
                    (const __attribute__((address_space(1))) unsigned int*)(gsrc + off),
                    (__attribute__((address_space(3))) unsigned int*)(ldst + off),
                    16, 0, 0);
        }
        const int cofs = cur*32768;
        #pragma unroll
        for (int p = 0; p < 8; ++p) {
            const int pos = kb*8 + p;
            const int pf  = (pos + 3 > 32) ? 32 : (pos + 3);   // compile-time
            Areg[(pos + 3) & 3] = *(const i32x8*)(abase + OFF[pf]); // dist-3
            if (p < 7) loadB(cofs, p + 1, Breg[(p + 1) & 1]);       // B dist-1
            __builtin_amdgcn_s_setprio(1);
            acc[0] = __builtin_amdgcn_mfma_scale_f32_32x32x64_f8f6f4(
                Areg[pos & 3], Breg[p & 1][0], acc[0], 0, 0, 0, 0x7F7F7F7F, 0, 0x7F7F7F7F);
            acc[1] = __builtin_amdgcn_mfma_scale_f32_32x32x64_f8f6f4(
                Areg[pos & 3], Breg[p & 1][1], acc[1], 0, 0, 0, 0x7F7F7F7F, 0, 0x7F7F7F7F);
            __builtin_amdgcn_s_setprio(0);
        }
        __syncthreads();          // drains this wave's DMA + publishes buffer
        cur ^= 1;
        loadB(cur*32768, 0, Breg[0]);                  // first B of next block
    }
    // tail: pos 32 (Areg[32&3]=Areg[0] prefetched at kb=3,p=5; Breg[0] just loaded)
    __builtin_amdgcn_s_setprio(1);
    acc[0] = __builtin_amdgcn_mfma_scale_f32_32x32x64_f8f6f4(
        Areg[0], Breg[0][0], acc[0], 0, 0, 0, 0x7F7F7F7F, 0, 0x7F7F7F7F);
    acc[1] = __builtin_amdgcn_mfma_scale_f32_32x32x64_f8f6f4(
        Areg[0], Breg[0][1], acc[1], 0, 0, 0, 0x7F7F7F7F, 0, 0x7F7F7F7F);
    __builtin_amdgcn_s_setprio(0);
    __syncthreads();              // all U reads done -> safe to overwrite as hid

    // ---- epilogue 1: acc/256 + hc2 - corrections, GELU, write hid (bf16) ----
    // 32x32 C/D layout: col = lane&31, row = (reg&3) + 8*(reg>>2) + 4*(lane>>5)
    const bool yedge = (y < 8) || (y >= 120);
    #pragma unroll
    for (int nt = 0; nt < 2; ++nt) {
        const int n = nt*32 + l31;
        const float hcv = hc2_l[n];
        const float cyv = yedge ? Cy_l[rib*64 + n] : 0.f;
        #pragma unroll
        for (int reg = 0; reg < 16; ++reg) {
            int row = (reg & 3) + 8*(reg >> 2) + 4*kg;
            int x = xw + row;
            float h = acc[nt][reg]*(1.0f/USCALE) + hcv - cyv;
            if (x < 8 || x >= 120) {
                int xi = (x < 8) ? x : (x - 112);
                h -= Cx_l[xi*64 + n];
                if (yedge) {                    // corner double-subtract fix
                    #pragma unroll
                    for (int di = 0; di < 4; ++di) {
                        int d = 1 << di;
                        int dyo = (y < d) ? 0 : ((y >= 128 - d) ? 2 : -1);
                        int dxo = (x < d) ? 0 : ((x >= 128 - d) ? 2 : -1);
                        if (dyo >= 0 && dxo >= 0)
                            h += V_l[(di*9 + dyo*3 + dxo)*64 + n];
                    }
                }
            }
            float u = 0.7978845608028654f * (h + 0.044715f*h*h*h);
            float g = h / (1.f + __expf(-2.f*u));
            hid[(rib*128 + x)*HID_S + n] = f2bf(g);
        }
    }
    // each wave reads back only its own 32 hid rows -> no barrier needed

    // ---- GEMM2: y = hid @ W2 + b2 (bf16, 16x16x32) ----
    f32x4 acc2[2][4];
    #pragma unroll
    for (int mt = 0; mt < 2; ++mt)
        #pragma unroll
        for (int nt = 0; nt < 4; ++nt) {
            acc2[mt][nt][0] = 0.f; acc2[mt][nt][1] = 0.f;
            acc2[mt][nt][2] = 0.f; acc2[mt][nt][3] = 0.f;
        }
    #pragma unroll
    for (int kc2 = 0; kc2 < 2; ++kc2) {
        s16x8 a2[2];
        #pragma unroll
        for (int mt = 0; mt < 2; ++mt)
            a2[mt] = *(const s16x8*)&hid[(rib*128 + xw + mt*16 + ln15)*HID_S + kc2*32 + oct*8];
        #pragma unroll
        for (int nt = 0; nt < 4; ++nt) {
            s16x8 bfr = *(const s16x8*)(W2s + ((size_t)(kc2*4 + nt)*64 + lane)*8);
            #pragma unroll
            for (int mt = 0; mt < 2; ++mt)
                acc2[mt][nt] = __builtin_amdgcn_mfma_f32_16x16x32_bf16(a2[mt], bfr, acc2[mt][nt], 0, 0, 0);
        }
    }

    float* ob = out + ((size_t)(b*128 + y))*128*64;
    #pragma unroll
    for (int nt = 0; nt < 4; ++nt) {
        const float b2v = b2[nt*16 + ln15];
        #pragma unroll
        for (int mt = 0; mt < 2; ++mt) {
            #pragma unroll
            for (int r = 0; r < 4; ++r) {
                int x = xw + mt*16 + oct*4 + r;
                ob[(size_t)x*64 + nt*16 + ln15] = acc2[mt][nt][r] + b2v;
            }
        }
    }
}

// ---------------- launch ----------------------------------------------------
extern "C" void kernel_launch(void* const* d_in, const int* in_sizes, int n_in,
                              void* d_out, int out_size, void* d_ws, size_t ws_size,
                              hipStream_t stream) {
    const float* x   = (const float*)d_in[0];
    const float* c   = (const float*)d_in[1];
    // d_in[2..5] = Wq,bq,Wk,bk : unused (softmax weights sum to 1 -> pool == v)
    const float* Wv  = (const float*)d_in[6];
    const float* bv  = (const float*)d_in[7];
    const float* Wo  = (const float*)d_in[8];
    const float* bo  = (const float*)d_in[9];
    const float* lng = (const float*)d_in[10];
    const float* lnb = (const float*)d_in[11];
    const float* pk  = (const float*)d_in[12];
    const float* W1  = (const float*)d_in[13];
    const float* b1  = (const float*)d_in[14];
    const float* W2  = (const float*)d_in[15];
    const float* b2  = (const float*)d_in[16];
    float* out = (float*)d_out;

    char* w = (char*)d_ws;
    unsigned char*  xpb = (unsigned char*)(w);                   // 10,616,832 B
    unsigned char*  Uf  = (unsigned char*)(w + 10616832);        //    135,168 B
    unsigned short* W2s = (unsigned short*)(w + 10752000);       //      8,192 B
    float*          V   = (float*)         (w + 10760192);       //     73,728 B
    float*          hcp = (float*)         (w + 10833920);       //      2,048 B (end 10,835,968)

    prep2<<<740, 256, 0, stream>>>(x, pk, W1, W2, b1, c, Wv, bv, Wo, bo, lng, lnb,
                                   xpb, Uf, W2s, V, hcp, out + 8388608);
    nca_main<<<512, 512, 0, stream>>>(xpb, Uf, W2s, V, hcp, b2, out);
}